// Round 3
// baseline (22431.519 us; speedup 1.0000x reference)
//
#include <hip/hip_runtime.h>

typedef __bf16 bf16;
typedef __bf16 bf16x4 __attribute__((ext_vector_type(4)));
typedef __bf16 bf16x8 __attribute__((ext_vector_type(8)));
typedef float f32x4 __attribute__((ext_vector_type(4)));
typedef unsigned int u32;
typedef unsigned long long u64;

#define T_STEPS 1024
#define BATCH 128
#define DIM 256      // D
#define HID 512      // H
#define NB 64        // blocks; block owns 8 h-columns (32 gate rows)

__device__ __forceinline__ f32x4 mfma_bf16(bf16x8 a, bf16x8 b, f32x4 c) {
  return __builtin_amdgcn_mfma_f32_16x16x32_bf16(a, b, c, 0, 0, 0);
}
__device__ __forceinline__ float fast_sigmoid(float v) {
  return __builtin_amdgcn_rcpf(1.f + __expf(-v));
}
__device__ __forceinline__ float fast_tanh(float v) {
  return 2.f * __builtin_amdgcn_rcpf(1.f + __expf(-2.f * v)) - 1.f;
}
// load 8 consecutive f32, convert to bf16x8 fragment
__device__ __forceinline__ bf16x8 cvt8(const float* p) {
  float4 a = *(const float4*)p;
  float4 b = *(const float4*)(p + 4);
  bf16x8 r;
  r[0] = (bf16)a.x; r[1] = (bf16)a.y; r[2] = (bf16)a.z; r[3] = (bf16)a.w;
  r[4] = (bf16)b.x; r[5] = (bf16)b.y; r[6] = (bf16)b.z; r[7] = (bf16)b.w;
  return r;
}
__device__ __forceinline__ u32 pack_bf16x2(float a, float b) {
  unsigned short lo = __builtin_bit_cast(unsigned short, (bf16)a);
  unsigned short hi = __builtin_bit_cast(unsigned short, (bf16)b);
  return (u32)lo | ((u32)hi << 16);
}
// device-coherent (agent-scope, sc1) 16B h-fragment load as 2x u64 atomics
__device__ __forceinline__ bf16x8 load_h8(const u64* p) {
  u64 lo = __hip_atomic_load(p, __ATOMIC_RELAXED, __HIP_MEMORY_SCOPE_AGENT);
  u64 hi = __hip_atomic_load(p + 1, __ATOMIC_RELAXED, __HIP_MEMORY_SCOPE_AGENT);
  bf16x4 l4 = __builtin_bit_cast(bf16x4, lo);
  bf16x4 h4 = __builtin_bit_cast(bf16x4, hi);
  bf16x8 r;
  r[0] = l4[0]; r[1] = l4[1]; r[2] = l4[2]; r[3] = l4[3];
  r[4] = h4[0]; r[5] = h4[1]; r[6] = h4[2]; r[7] = h4[3];
  return r;
}

// ws layout: [0..127] barrier (cnt, gen), [128 ..] hbuf[2][128*512] bf16
__global__ __launch_bounds__(256) void lstm_persist(
    const float* __restrict__ x, const float* __restrict__ Wx,
    const float* __restrict__ bx, const float* __restrict__ Wh,
    const float* __restrict__ bh, const float* __restrict__ Wfc,
    const float* __restrict__ bfc, float* __restrict__ out,
    u32* bar, bf16* hbuf) {
  const int tid = threadIdx.x;
  const int bid = blockIdx.x;
  const int wave = tid >> 6;
  const int lane = tid & 63;
  const int n = lane & 15;      // MFMA column / A-row selector
  const int quad = lane >> 4;   // k-chunk selector
  const int sub = n & 3;        // gate-sub within 4-group
  const int m0 = wave * 32;     // this wave's batch base (2 M-tiles)

  // Column mapping: B-tile nt, local row nn (0..15): gate g = nn>>2, sub = nn&3
  //   h column = bid*8 + 2*sub + nt   (so lane's nt=0/1 outputs are ADJACENT)
  // LDS local row r (0..31): nt = r>>4, nn = r&15:
  //   global gate row R = ((r&15)>>2)*HID + bid*8 + 2*(r&3) + (r>>4)
  __shared__ bf16 lds_wh[32][520];
  __shared__ bf16 lds_wx[32][264];

  for (int idx = tid; idx < 32 * 128; idx += 256) {
    int r = idx >> 7, c = (idx & 127) * 4;
    int R = ((r & 15) >> 2) * HID + bid * 8 + 2 * (r & 3) + (r >> 4);
    float4 v = *(const float4*)(Wh + R * HID + c);
    bf16x4 w; w[0] = (bf16)v.x; w[1] = (bf16)v.y; w[2] = (bf16)v.z; w[3] = (bf16)v.w;
    *(bf16x4*)(&lds_wh[r][c]) = w;
  }
  for (int idx = tid; idx < 32 * 64; idx += 256) {
    int r = idx >> 6, c = (idx & 63) * 4;
    int R = ((r & 15) >> 2) * HID + bid * 8 + 2 * (r & 3) + (r >> 4);
    float4 v = *(const float4*)(Wx + R * DIM + c);
    bf16x4 w; w[0] = (bf16)v.x; w[1] = (bf16)v.y; w[2] = (bf16)v.z; w[3] = (bf16)v.w;
    *(bf16x4*)(&lds_wx[r][c]) = w;
  }

  // per-lane gate biases (bx+bh) for my two N-tiles
  int R0 = (n >> 2) * HID + bid * 8 + 2 * sub + 0;
  int R1 = (n >> 2) * HID + bid * 8 + 2 * sub + 1;
  float bias0 = bx[R0] + bh[R0];
  float bias1 = bx[R1] + bh[R1];

  __syncthreads();

  // cell state in f32 registers (meaningful on lanes n<4): [mt][nt][reg]
  float cst[2][2][4];
#pragma unroll
  for (int a = 0; a < 2; ++a)
#pragma unroll
    for (int b = 0; b < 2; ++b)
#pragma unroll
      for (int r = 0; r < 4; ++r) cst[a][b][r] = 0.f;

  u32* cnt = bar;
  u32* gen = bar + 1;
  const int srcf = (lane & 48) | (4 + sub);
  const int srcg = (lane & 48) | (8 + sub);
  const int srco = (lane & 48) | (12 + sub);

  const f32x4 b0v = {bias0, bias0, bias0, bias0};
  const f32x4 b1v = {bias1, bias1, bias1, bias1};

  for (int t = 0; t < T_STEPS; ++t) {
    const bf16* hrd = hbuf + (t & 1) * (BATCH * HID);
    bf16* hwr = hbuf + ((t + 1) & 1) * (BATCH * HID);

    f32x4 acc00 = b0v, acc01 = b1v, acc10 = b0v, acc11 = b1v;

    // ---- h @ Wh^T (K = 512); h via device-coherent (sc1) loads ----
    const u64* h0q = (const u64*)hrd + ((m0 + n) * HID) / 4 + quad * 2;
    const u64* h1q = h0q + (16 * HID) / 4;
#pragma unroll
    for (int k = 0; k < HID; k += 32) {
      bf16x8 A0 = load_h8(h0q + k / 4);
      bf16x8 A1 = load_h8(h1q + k / 4);
      bf16x8 B0 = *(const bf16x8*)(&lds_wh[n][quad * 8 + k]);
      bf16x8 B1 = *(const bf16x8*)(&lds_wh[16 + n][quad * 8 + k]);
      acc00 = mfma_bf16(A0, B0, acc00);
      acc01 = mfma_bf16(A0, B1, acc01);
      acc10 = mfma_bf16(A1, B0, acc10);
      acc11 = mfma_bf16(A1, B1, acc11);
    }
    // ---- x_t @ Wx^T (K = 256), f32 input converted on the fly (plain cached) ----
    const float* x0p = x + (size_t)((m0 + n) * 1024 + t) * DIM + quad * 8;
    const float* x1p = x0p + (size_t)16 * 1024 * DIM;
#pragma unroll
    for (int k = 0; k < DIM; k += 32) {
      bf16x8 A0 = cvt8(x0p + k);
      bf16x8 A1 = cvt8(x1p + k);
      bf16x8 B0 = *(const bf16x8*)(&lds_wx[n][quad * 8 + k]);
      bf16x8 B1 = *(const bf16x8*)(&lds_wx[16 + n][quad * 8 + k]);
      acc00 = mfma_bf16(A0, B0, acc00);
      acc01 = mfma_bf16(A0, B1, acc01);
      acc10 = mfma_bf16(A1, B0, acc10);
      acc11 = mfma_bf16(A1, B1, acc11);
    }

    // ---- gate nonlinearities + cell update ----
    // acc layout: col n = lane&15 (gate = n>>2, sub = n&3), row = quad*4 + r
    f32x4 accs[2][2] = {{acc00, acc01}, {acc10, acc11}};
#pragma unroll
    for (int mt = 0; mt < 2; ++mt) {
#pragma unroll
      for (int r = 0; r < 4; ++r) {
        float hn[2];
#pragma unroll
        for (int nt = 0; nt < 2; ++nt) {
          float v = accs[mt][nt][r];
          float s = fast_sigmoid(v);
          float th = fast_tanh(v);
          float pv = (n >= 8 && n < 12) ? th : s;  // g-gate lanes: tanh
          float fv = __shfl(pv, srcf, 64);
          float gv = __shfl(pv, srcg, 64);
          float ov = __shfl(pv, srco, 64);
          float cn = cst[mt][nt][r] * fv + pv * gv;  // pv == i on lanes n<4
          hn[nt] = ov * fast_tanh(cn);
          cst[mt][nt][r] = cn;
        }
        if (n < 4) {
          int m = m0 + mt * 16 + quad * 4 + r;
          int c0 = bid * 8 + 2 * n;  // adjacent pair (c0, c0+1)
          u32 pk = pack_bf16x2(hn[0], hn[1]);
          __hip_atomic_store((u32*)(hwr + m * HID + c0), pk,
                             __ATOMIC_RELAXED, __HIP_MEMORY_SCOPE_AGENT);
          if (t == T_STEPS - 1) {
            out[m * HID + c0] = hn[0];
            out[m * HID + c0 + 1] = hn[1];
          }
        }
      }
    }

    // ---- grid barrier: NO cache-maintenance fences ----
    // __syncthreads drains vmcnt(0) per wave -> all sc1 h-stores are globally
    // visible before tid0 arms the counter. Readers' sc1 loads always fetch
    // the coherence point, so no acquire-invalidate is needed.
    __atomic_signal_fence(__ATOMIC_SEQ_CST);
    __syncthreads();
    if (tid == 0) {
      u32 g = __hip_atomic_load(gen, __ATOMIC_RELAXED, __HIP_MEMORY_SCOPE_AGENT);
      u32 a = __hip_atomic_fetch_add(cnt, 1u, __ATOMIC_RELAXED, __HIP_MEMORY_SCOPE_AGENT);
      if (a == NB - 1) {
        __hip_atomic_store(cnt, 0u, __ATOMIC_RELAXED, __HIP_MEMORY_SCOPE_AGENT);
        __hip_atomic_fetch_add(gen, 1u, __ATOMIC_RELAXED, __HIP_MEMORY_SCOPE_AGENT);
      } else {
        while (__hip_atomic_load(gen, __ATOMIC_RELAXED, __HIP_MEMORY_SCOPE_AGENT) == g) {
          __builtin_amdgcn_s_sleep(2);
        }
      }
    }
    __syncthreads();
    __atomic_signal_fence(__ATOMIC_SEQ_CST);
  }

  // ---- final fc: out2[b][o] = hT @ Wfc^T + bfc (blocks 0..7, 16 cols each) ----
  if (bid < 8) {
    float* out2 = out + BATCH * HID;
    int col = bid * 16 + n;
    float bv = bfc[col];
#pragma unroll
    for (int mt = 0; mt < 2; ++mt) {
      int mb = wave * 32 + mt * 16;
      f32x4 a4 = {bv, bv, bv, bv};
      const u64* ar = (const u64*)hbuf + ((mb + n) * HID) / 4 + quad * 2;  // hT = buffer 0
      const float* br = Wfc + col * HID + quad * 8;
#pragma unroll
      for (int k = 0; k < HID; k += 32) {
        bf16x8 A = load_h8(ar + k / 4);
        bf16x8 B = cvt8(br + k);
        a4 = mfma_bf16(A, B, a4);
      }
#pragma unroll
      for (int r = 0; r < 4; ++r) {
        out2[(mb + quad * 4 + r) * 128 + col] = a4[r];
      }
    }
  }
}

extern "C" void kernel_launch(void* const* d_in, const int* in_sizes, int n_in,
                              void* d_out, int out_size, void* d_ws, size_t ws_size,
                              hipStream_t stream) {
  (void)in_sizes; (void)n_in; (void)out_size; (void)ws_size;
  const float* x   = (const float*)d_in[0];
  const float* Wx  = (const float*)d_in[2];
  const float* bx  = (const float*)d_in[3];
  const float* Wh  = (const float*)d_in[4];
  const float* bh  = (const float*)d_in[5];
  const float* Wfc = (const float*)d_in[8];
  const float* bfc = (const float*)d_in[9];
  float* out = (float*)d_out;
  u32* bar = (u32*)d_ws;
  bf16* hbuf = (bf16*)((char*)d_ws + 128);

  // zero barrier state + both h buffers (h0 = 0); memset kernel's stores are
  // flushed at its dispatch end, so our sc1 reads see the zeros.
  hipMemsetAsync(d_ws, 0, 128 + 2 * BATCH * HID * sizeof(bf16), stream);
  lstm_persist<<<dim3(NB), dim3(256), 0, stream>>>(x, Wx, bx, Wh, bh, Wfc, bfc,
                                                   out, bar, hbuf);
}

// Round 4
// 13552.319 us; speedup vs baseline: 1.6552x; 1.6552x over previous
//
#include <hip/hip_runtime.h>

typedef __bf16 bf16;
typedef __bf16 bf16x4 __attribute__((ext_vector_type(4)));
typedef __bf16 bf16x8 __attribute__((ext_vector_type(8)));
typedef float f32x4 __attribute__((ext_vector_type(4)));
typedef unsigned int u32;
typedef unsigned long long u64;

#define T_STEPS 1024
#define BATCH 128
#define DIM 256      // D
#define HID 512      // H
#define NB 64        // blocks; block owns 8 h-columns (32 gate rows)

__device__ __forceinline__ f32x4 mfma_bf16(bf16x8 a, bf16x8 b, f32x4 c) {
  return __builtin_amdgcn_mfma_f32_16x16x32_bf16(a, b, c, 0, 0, 0);
}
__device__ __forceinline__ float fast_sigmoid(float v) {
  return __builtin_amdgcn_rcpf(1.f + __expf(-v));
}
__device__ __forceinline__ float fast_tanh(float v) {
  return 2.f * __builtin_amdgcn_rcpf(1.f + __expf(-2.f * v)) - 1.f;
}
__device__ __forceinline__ bf16x8 cvt8(const float* p) {
  float4 a = *(const float4*)p;
  float4 b = *(const float4*)(p + 4);
  bf16x8 r;
  r[0] = (bf16)a.x; r[1] = (bf16)a.y; r[2] = (bf16)a.z; r[3] = (bf16)a.w;
  r[4] = (bf16)b.x; r[5] = (bf16)b.y; r[6] = (bf16)b.z; r[7] = (bf16)b.w;
  return r;
}
__device__ __forceinline__ u32 pack_bf16x2(float a, float b) {
  unsigned short lo = __builtin_bit_cast(unsigned short, (bf16)a);
  unsigned short hi = __builtin_bit_cast(unsigned short, (bf16)b);
  return (u32)lo | ((u32)hi << 16);
}
// device-coherent (agent-scope, sc1) 16B h-fragment load as 2x u64 atomics
__device__ __forceinline__ bf16x8 load_h8(const u64* p) {
  u64 lo = __hip_atomic_load(p, __ATOMIC_RELAXED, __HIP_MEMORY_SCOPE_AGENT);
  u64 hi = __hip_atomic_load(p + 1, __ATOMIC_RELAXED, __HIP_MEMORY_SCOPE_AGENT);
  bf16x4 l4 = __builtin_bit_cast(bf16x4, lo);
  bf16x4 h4 = __builtin_bit_cast(bf16x4, hi);
  bf16x8 r;
  r[0] = l4[0]; r[1] = l4[1]; r[2] = l4[2]; r[3] = l4[3];
  r[4] = h4[0]; r[5] = h4[1]; r[6] = h4[2]; r[7] = h4[3];
  return r;
}

// wave-parallel wait: lane i polls flags[i*16] until all >= target.
// One pipelined sc1 load per lane per round -> one L3 round-trip per poll.
__device__ __forceinline__ void wait_flags(const u32* flags, int lane, u32 target) {
  const u32* my = flags + lane * 16;
  u32 f = __hip_atomic_load(my, __ATOMIC_RELAXED, __HIP_MEMORY_SCOPE_AGENT);
  while (!__all(f >= target)) {
    __builtin_amdgcn_s_sleep(1);
    f = __hip_atomic_load(my, __ATOMIC_RELAXED, __HIP_MEMORY_SCOPE_AGENT);
  }
}

// ws layout: [0..4095] flags[64] (one per 64B line), [4096 ..] hbuf[2][128*512] bf16
__global__ __launch_bounds__(256) void lstm_persist(
    const float* __restrict__ x, const float* __restrict__ Wx,
    const float* __restrict__ bx, const float* __restrict__ Wh,
    const float* __restrict__ bh, const float* __restrict__ Wfc,
    const float* __restrict__ bfc, float* __restrict__ out,
    u32* flags, bf16* hbuf) {
  const int tid = threadIdx.x;
  const int bid = blockIdx.x;
  const int wave = tid >> 6;
  const int lane = tid & 63;
  const int n = lane & 15;      // MFMA column / A-row selector
  const int quad = lane >> 4;   // k-chunk selector
  const int sub = n & 3;        // gate-sub within 4-group
  const int m0 = wave * 32;     // this wave's batch base (2 M-tiles)

  // Column mapping: B-tile nt, local row nn (0..15): gate g = nn>>2, sub = nn&3
  //   h column = bid*8 + 2*sub + nt   (lane's nt=0/1 outputs are ADJACENT)
  __shared__ bf16 lds_wh[32][520];
  __shared__ bf16 lds_wx[32][264];

  for (int idx = tid; idx < 32 * 128; idx += 256) {
    int r = idx >> 7, c = (idx & 127) * 4;
    int R = ((r & 15) >> 2) * HID + bid * 8 + 2 * (r & 3) + (r >> 4);
    float4 v = *(const float4*)(Wh + R * HID + c);
    bf16x4 w; w[0] = (bf16)v.x; w[1] = (bf16)v.y; w[2] = (bf16)v.z; w[3] = (bf16)v.w;
    *(bf16x4*)(&lds_wh[r][c]) = w;
  }
  for (int idx = tid; idx < 32 * 64; idx += 256) {
    int r = idx >> 6, c = (idx & 63) * 4;
    int R = ((r & 15) >> 2) * HID + bid * 8 + 2 * (r & 3) + (r >> 4);
    float4 v = *(const float4*)(Wx + R * DIM + c);
    bf16x4 w; w[0] = (bf16)v.x; w[1] = (bf16)v.y; w[2] = (bf16)v.z; w[3] = (bf16)v.w;
    *(bf16x4*)(&lds_wx[r][c]) = w;
  }

  int R0 = (n >> 2) * HID + bid * 8 + 2 * sub + 0;
  int R1 = (n >> 2) * HID + bid * 8 + 2 * sub + 1;
  float bias0 = bx[R0] + bh[R0];
  float bias1 = bx[R1] + bh[R1];

  __syncthreads();

  float cst[2][2][4];
#pragma unroll
  for (int a = 0; a < 2; ++a)
#pragma unroll
    for (int b = 0; b < 2; ++b)
#pragma unroll
      for (int r = 0; r < 4; ++r) cst[a][b][r] = 0.f;

  const int srcf = (lane & 48) | (4 + sub);
  const int srcg = (lane & 48) | (8 + sub);
  const int srco = (lane & 48) | (12 + sub);

  const f32x4 b0v = {bias0, bias0, bias0, bias0};
  const f32x4 b1v = {bias1, bias1, bias1, bias1};

  for (int t = 0; t < T_STEPS; ++t) {
    const bf16* hrd = hbuf + (t & 1) * (BATCH * HID);
    bf16* hwr = hbuf + ((t + 1) & 1) * (BATCH * HID);

    f32x4 acc00 = b0v, acc01 = b1v, acc10 = b0v, acc11 = b1v;

    // ---- x_t @ Wx^T first: independent of other blocks, hides poll+load latency ----
    const float* x0p = x + (size_t)((m0 + n) * 1024 + t) * DIM + quad * 8;
    const float* x1p = x0p + (size_t)16 * 1024 * DIM;
#pragma unroll
    for (int k = 0; k < DIM; k += 32) {
      bf16x8 A0 = cvt8(x0p + k);
      bf16x8 A1 = cvt8(x1p + k);
      bf16x8 B0 = *(const bf16x8*)(&lds_wx[n][quad * 8 + k]);
      bf16x8 B1 = *(const bf16x8*)(&lds_wx[16 + n][quad * 8 + k]);
      acc00 = mfma_bf16(A0, B0, acc00);
      acc01 = mfma_bf16(A0, B1, acc01);
      acc10 = mfma_bf16(A1, B0, acc10);
      acc11 = mfma_bf16(A1, B1, acc11);
    }

    // ---- wait until all blocks have finished step t-1 (h[t&1] complete) ----
    wait_flags(flags, lane, (u32)t);

    // ---- h @ Wh^T (K = 512); h via device-coherent (sc1) loads ----
    const u64* h0q = (const u64*)hrd + ((m0 + n) * HID) / 4 + quad * 2;
    const u64* h1q = h0q + (16 * HID) / 4;
#pragma unroll
    for (int k = 0; k < HID; k += 32) {
      bf16x8 A0 = load_h8(h0q + k / 4);
      bf16x8 A1 = load_h8(h1q + k / 4);
      bf16x8 B0 = *(const bf16x8*)(&lds_wh[n][quad * 8 + k]);
      bf16x8 B1 = *(const bf16x8*)(&lds_wh[16 + n][quad * 8 + k]);
      acc00 = mfma_bf16(A0, B0, acc00);
      acc01 = mfma_bf16(A0, B1, acc01);
      acc10 = mfma_bf16(A1, B0, acc10);
      acc11 = mfma_bf16(A1, B1, acc11);
    }

    // ---- gate nonlinearities + cell update ----
    f32x4 accs[2][2] = {{acc00, acc01}, {acc10, acc11}};
#pragma unroll
    for (int mt = 0; mt < 2; ++mt) {
#pragma unroll
      for (int r = 0; r < 4; ++r) {
        float hn[2];
#pragma unroll
        for (int nt = 0; nt < 2; ++nt) {
          float v = accs[mt][nt][r];
          float s = fast_sigmoid(v);
          float th = fast_tanh(v);
          float pv = (n >= 8 && n < 12) ? th : s;  // g-gate lanes: tanh
          float fv = __shfl(pv, srcf, 64);
          float gv = __shfl(pv, srcg, 64);
          float ov = __shfl(pv, srco, 64);
          float cn = cst[mt][nt][r] * fv + pv * gv;  // pv == i on lanes n<4
          hn[nt] = ov * fast_tanh(cn);
          cst[mt][nt][r] = cn;
        }
        if (n < 4) {
          int m = m0 + mt * 16 + quad * 4 + r;
          int c0 = bid * 8 + 2 * n;  // adjacent pair (c0, c0+1)
          u32 pk = pack_bf16x2(hn[0], hn[1]);
          __hip_atomic_store((u32*)(hwr + m * HID + c0), pk,
                             __ATOMIC_RELAXED, __HIP_MEMORY_SCOPE_AGENT);
          if (t == T_STEPS - 1) {
            out[m * HID + c0] = hn[0];
            out[m * HID + c0 + 1] = hn[1];
          }
        }
      }
    }

    // ---- publish: one flag per block, own cache line, no RMW, no reset ----
    // __syncthreads drains every wave's vmcnt -> all sc1 h-stores of this
    // block are globally visible before tid0's flag store issues.
    __syncthreads();
    if (tid == 0) {
      __hip_atomic_store(flags + bid * 16, (u32)(t + 1),
                         __ATOMIC_RELAXED, __HIP_MEMORY_SCOPE_AGENT);
    }
  }

  // ---- final fc: out2[b][o] = hT @ Wfc^T + bfc (blocks 0..7, 16 cols each) ----
  if (bid < 8) {
    wait_flags(flags, lane, (u32)T_STEPS);  // all blocks' final h written
    float* out2 = out + BATCH * HID;
    int col = bid * 16 + n;
    float bv = bfc[col];
#pragma unroll
    for (int mt = 0; mt < 2; ++mt) {
      int mb = wave * 32 + mt * 16;
      f32x4 a4 = {bv, bv, bv, bv};
      const u64* ar = (const u64*)hbuf + ((mb + n) * HID) / 4 + quad * 2;  // hT = buffer 0
      const float* br = Wfc + col * HID + quad * 8;
#pragma unroll
      for (int k = 0; k < HID; k += 32) {
        bf16x8 A = load_h8(ar + k / 4);
        bf16x8 B = cvt8(br + k);
        a4 = mfma_bf16(A, B, a4);
      }
#pragma unroll
      for (int r = 0; r < 4; ++r) {
        out2[(mb + quad * 4 + r) * 128 + col] = a4[r];
      }
    }
  }
}

extern "C" void kernel_launch(void* const* d_in, const int* in_sizes, int n_in,
                              void* d_out, int out_size, void* d_ws, size_t ws_size,
                              hipStream_t stream) {
  (void)in_sizes; (void)n_in; (void)out_size; (void)ws_size;
  const float* x   = (const float*)d_in[0];
  const float* Wx  = (const float*)d_in[2];
  const float* bx  = (const float*)d_in[3];
  const float* Wh  = (const float*)d_in[4];
  const float* bh  = (const float*)d_in[5];
  const float* Wfc = (const float*)d_in[8];
  const float* bfc = (const float*)d_in[9];
  float* out = (float*)d_out;
  u32* flags = (u32*)d_ws;
  bf16* hbuf = (bf16*)((char*)d_ws + 4096);

  // zero flags + both h buffers (h0 = 0); ws is re-poisoned before every launch
  hipMemsetAsync(d_ws, 0, 4096 + 2 * BATCH * HID * sizeof(bf16), stream);
  lstm_persist<<<dim3(NB), dim3(256), 0, stream>>>(x, Wx, bx, Wh, bh, Wfc, bfc,
                                                   out, flags, hbuf);
}

// Round 5
// 13321.883 us; speedup vs baseline: 1.6838x; 1.0173x over previous
//
#include <hip/hip_runtime.h>

typedef __bf16 bf16;
typedef __bf16 bf16x4 __attribute__((ext_vector_type(4)));
typedef __bf16 bf16x8 __attribute__((ext_vector_type(8)));
typedef float f32x4 __attribute__((ext_vector_type(4)));
typedef unsigned int u32;
typedef unsigned long long u64;

#define T_STEPS 1024
#define BATCH 128
#define DIM 256      // D
#define HID 512      // H
#define NB 64        // blocks; block owns 8 h-columns (32 gate rows)

__device__ __forceinline__ f32x4 mfma_bf16(bf16x8 a, bf16x8 b, f32x4 c) {
  return __builtin_amdgcn_mfma_f32_16x16x32_bf16(a, b, c, 0, 0, 0);
}
__device__ __forceinline__ float fast_sigmoid(float v) {
  return __builtin_amdgcn_rcpf(1.f + __expf(-v));
}
__device__ __forceinline__ float fast_tanh(float v) {
  return 2.f * __builtin_amdgcn_rcpf(1.f + __expf(-2.f * v)) - 1.f;
}
__device__ __forceinline__ bf16x8 cvt8(const float* p) {
  float4 a = *(const float4*)p;
  float4 b = *(const float4*)(p + 4);
  bf16x8 r;
  r[0] = (bf16)a.x; r[1] = (bf16)a.y; r[2] = (bf16)a.z; r[3] = (bf16)a.w;
  r[4] = (bf16)b.x; r[5] = (bf16)b.y; r[6] = (bf16)b.z; r[7] = (bf16)b.w;
  return r;
}
__device__ __forceinline__ u32 pack_bf16x2(float a, float b) {
  unsigned short lo = __builtin_bit_cast(unsigned short, (bf16)a);
  unsigned short hi = __builtin_bit_cast(unsigned short, (bf16)b);
  return (u32)lo | ((u32)hi << 16);
}
__device__ __forceinline__ bf16x8 combine(u64 lo, u64 hi) {
  bf16x4 l4 = __builtin_bit_cast(bf16x4, lo);
  bf16x4 h4 = __builtin_bit_cast(bf16x4, hi);
  bf16x8 r;
  r[0] = l4[0]; r[1] = l4[1]; r[2] = l4[2]; r[3] = l4[3];
  r[4] = h4[0]; r[5] = h4[1]; r[6] = h4[2]; r[7] = h4[3];
  return r;
}
__device__ __forceinline__ u64 ld_agent(const u64* p) {
  return __hip_atomic_load(p, __ATOMIC_RELAXED, __HIP_MEMORY_SCOPE_AGENT);
}

// wave-parallel wait: lane i polls flags[i*16] until all >= target.
__device__ __forceinline__ void wait_flags(const u32* flags, int lane, u32 target) {
  const u32* my = flags + lane * 16;
  u32 f = __hip_atomic_load(my, __ATOMIC_RELAXED, __HIP_MEMORY_SCOPE_AGENT);
  while (!__all(f >= target)) {
    __builtin_amdgcn_s_sleep(1);
    f = __hip_atomic_load(my, __ATOMIC_RELAXED, __HIP_MEMORY_SCOPE_AGENT);
  }
}

// ws layout: [0..4095] flags[64] (one per 64B line), [4096 ..] hbuf[2][128*512] bf16
__global__ __launch_bounds__(256, 1) void lstm_persist(
    const float* __restrict__ x, const float* __restrict__ Wx,
    const float* __restrict__ bx, const float* __restrict__ Wh,
    const float* __restrict__ bh, const float* __restrict__ Wfc,
    const float* __restrict__ bfc, float* __restrict__ out,
    u32* flags, bf16* hbuf) {
  const int tid = threadIdx.x;
  const int bid = blockIdx.x;
  const int wave = tid >> 6;
  const int lane = tid & 63;
  const int n = lane & 15;      // MFMA column / A-row selector
  const int quad = lane >> 4;   // k-chunk selector
  const int sub = n & 3;        // gate-sub within 4-group
  const int m0 = wave * 32;     // this wave's batch base (2 M-tiles)

  // Column mapping: B-tile nt, local row nn (0..15): gate g = nn>>2, sub = nn&3
  //   h column = bid*8 + 2*sub + nt   (lane's nt=0/1 outputs are ADJACENT)
  __shared__ bf16 lds_wh[32][520];
  __shared__ bf16 lds_wx[32][264];

  for (int idx = tid; idx < 32 * 128; idx += 256) {
    int r = idx >> 7, c = (idx & 127) * 4;
    int R = ((r & 15) >> 2) * HID + bid * 8 + 2 * (r & 3) + (r >> 4);
    float4 v = *(const float4*)(Wh + R * HID + c);
    bf16x4 w; w[0] = (bf16)v.x; w[1] = (bf16)v.y; w[2] = (bf16)v.z; w[3] = (bf16)v.w;
    *(bf16x4*)(&lds_wh[r][c]) = w;
  }
  for (int idx = tid; idx < 32 * 64; idx += 256) {
    int r = idx >> 6, c = (idx & 63) * 4;
    int R = ((r & 15) >> 2) * HID + bid * 8 + 2 * (r & 3) + (r >> 4);
    float4 v = *(const float4*)(Wx + R * DIM + c);
    bf16x4 w; w[0] = (bf16)v.x; w[1] = (bf16)v.y; w[2] = (bf16)v.z; w[3] = (bf16)v.w;
    *(bf16x4*)(&lds_wx[r][c]) = w;
  }

  int R0 = (n >> 2) * HID + bid * 8 + 2 * sub + 0;
  int R1 = (n >> 2) * HID + bid * 8 + 2 * sub + 1;
  float bias0 = bx[R0] + bh[R0];
  float bias1 = bx[R1] + bh[R1];

  __syncthreads();

  float cst[2][2][4];
#pragma unroll
  for (int a = 0; a < 2; ++a)
#pragma unroll
    for (int b = 0; b < 2; ++b)
#pragma unroll
      for (int r = 0; r < 4; ++r) cst[a][b][r] = 0.f;

  const int srcf = (lane & 48) | (4 + sub);
  const int srcg = (lane & 48) | (8 + sub);
  const int srco = (lane & 48) | (12 + sub);

  const f32x4 b0v = {bias0, bias0, bias0, bias0};
  const f32x4 b1v = {bias1, bias1, bias1, bias1};

  for (int t = 0; t < T_STEPS; ++t) {
    const bf16* hrd = hbuf + (t & 1) * (BATCH * HID);
    bf16* hwr = hbuf + ((t + 1) & 1) * (BATCH * HID);

    f32x4 acc00 = b0v, acc01 = b1v, acc10 = b0v, acc11 = b1v;

    // ---- x_t @ Wx^T first: independent of other blocks, hides latency under
    // barrier skew ----
    const float* x0p = x + (size_t)((m0 + n) * 1024 + t) * DIM + quad * 8;
    const float* x1p = x0p + (size_t)16 * 1024 * DIM;
#pragma unroll
    for (int k = 0; k < DIM; k += 32) {
      bf16x8 A0 = cvt8(x0p + k);
      bf16x8 A1 = cvt8(x1p + k);
      bf16x8 B0 = *(const bf16x8*)(&lds_wx[n][quad * 8 + k]);
      bf16x8 B1 = *(const bf16x8*)(&lds_wx[16 + n][quad * 8 + k]);
      acc00 = mfma_bf16(A0, B0, acc00);
      acc01 = mfma_bf16(A0, B1, acc01);
      acc10 = mfma_bf16(A1, B0, acc10);
      acc11 = mfma_bf16(A1, B1, acc11);
    }

    // ---- wait until all blocks have finished step t-1 (h[t&1] complete) ----
    wait_flags(flags, lane, (u32)t);

    // ---- BATCHED h loads: all 64 agent-scope u64 loads issued back-to-back
    // (single L3 round-trip for the whole phase), THEN the MFMA loop consumes
    // them in load order. 128 VGPRs; fine at 1 block/CU (launch_bounds(256,1)).
    const u64* h0q = (const u64*)hrd + ((m0 + n) * HID) / 4 + quad * 2;
    const u64* h1q = h0q + (16 * HID) / 4;
    u64 hv[64];
#pragma unroll
    for (int k = 0; k < 16; ++k) {
      hv[4 * k + 0] = ld_agent(h0q + 8 * k + 0);
      hv[4 * k + 1] = ld_agent(h0q + 8 * k + 1);
      hv[4 * k + 2] = ld_agent(h1q + 8 * k + 0);
      hv[4 * k + 3] = ld_agent(h1q + 8 * k + 1);
    }
#pragma unroll
    for (int k = 0; k < 16; ++k) {
      bf16x8 A0 = combine(hv[4 * k + 0], hv[4 * k + 1]);
      bf16x8 A1 = combine(hv[4 * k + 2], hv[4 * k + 3]);
      bf16x8 B0 = *(const bf16x8*)(&lds_wh[n][quad * 8 + k * 32]);
      bf16x8 B1 = *(const bf16x8*)(&lds_wh[16 + n][quad * 8 + k * 32]);
      acc00 = mfma_bf16(A0, B0, acc00);
      acc01 = mfma_bf16(A0, B1, acc01);
      acc10 = mfma_bf16(A1, B0, acc10);
      acc11 = mfma_bf16(A1, B1, acc11);
    }

    // ---- gate nonlinearities + cell update ----
    f32x4 accs[2][2] = {{acc00, acc01}, {acc10, acc11}};
#pragma unroll
    for (int mt = 0; mt < 2; ++mt) {
#pragma unroll
      for (int r = 0; r < 4; ++r) {
        float hn[2];
#pragma unroll
        for (int nt = 0; nt < 2; ++nt) {
          float v = accs[mt][nt][r];
          float s = fast_sigmoid(v);
          float th = fast_tanh(v);
          float pv = (n >= 8 && n < 12) ? th : s;  // g-gate lanes: tanh
          float fv = __shfl(pv, srcf, 64);
          float gv = __shfl(pv, srcg, 64);
          float ov = __shfl(pv, srco, 64);
          float cn = cst[mt][nt][r] * fv + pv * gv;  // pv == i on lanes n<4
          hn[nt] = ov * fast_tanh(cn);
          cst[mt][nt][r] = cn;
        }
        if (n < 4) {
          int m = m0 + mt * 16 + quad * 4 + r;
          int c0 = bid * 8 + 2 * n;  // adjacent pair (c0, c0+1)
          u32 pk = pack_bf16x2(hn[0], hn[1]);
          __hip_atomic_store((u32*)(hwr + m * HID + c0), pk,
                             __ATOMIC_RELAXED, __HIP_MEMORY_SCOPE_AGENT);
          if (t == T_STEPS - 1) {
            out[m * HID + c0] = hn[0];
            out[m * HID + c0 + 1] = hn[1];
          }
        }
      }
    }

    // ---- publish: one flag per block, own cache line, no RMW, no reset ----
    // __syncthreads drains every wave's vmcnt -> all sc1 h-stores of this
    // block are globally visible before tid0's flag store issues.
    __syncthreads();
    if (tid == 0) {
      __hip_atomic_store(flags + bid * 16, (u32)(t + 1),
                         __ATOMIC_RELAXED, __HIP_MEMORY_SCOPE_AGENT);
    }
  }

  // ---- final fc: out2[b][o] = hT @ Wfc^T + bfc (blocks 0..7, 16 cols each) ----
  if (bid < 8) {
    wait_flags(flags, lane, (u32)T_STEPS);  // all blocks' final h written
    float* out2 = out + BATCH * HID;
    int col = bid * 16 + n;
    float bv = bfc[col];
#pragma unroll
    for (int mt = 0; mt < 2; ++mt) {
      int mb = wave * 32 + mt * 16;
      f32x4 a4 = {bv, bv, bv, bv};
      const u64* ar = (const u64*)hbuf + ((mb + n) * HID) / 4 + quad * 2;  // hT = buffer 0
      const float* br = Wfc + col * HID + quad * 8;
#pragma unroll
      for (int k = 0; k < HID; k += 32) {
        bf16x8 A = combine(ld_agent(ar + k / 4), ld_agent(ar + k / 4 + 1));
        bf16x8 B = cvt8(br + k);
        a4 = mfma_bf16(A, B, a4);
      }
#pragma unroll
      for (int r = 0; r < 4; ++r) {
        out2[(mb + quad * 4 + r) * 128 + col] = a4[r];
      }
    }
  }
}

extern "C" void kernel_launch(void* const* d_in, const int* in_sizes, int n_in,
                              void* d_out, int out_size, void* d_ws, size_t ws_size,
                              hipStream_t stream) {
  (void)in_sizes; (void)n_in; (void)out_size; (void)ws_size;
  const float* x   = (const float*)d_in[0];
  const float* Wx  = (const float*)d_in[2];
  const float* bx  = (const float*)d_in[3];
  const float* Wh  = (const float*)d_in[4];
  const float* bh  = (const float*)d_in[5];
  const float* Wfc = (const float*)d_in[8];
  const float* bfc = (const float*)d_in[9];
  float* out = (float*)d_out;
  u32* flags = (u32*)d_ws;
  bf16* hbuf = (bf16*)((char*)d_ws + 4096);

  // zero flags + both h buffers (h0 = 0); ws is re-poisoned before every launch
  hipMemsetAsync(d_ws, 0, 4096 + 2 * BATCH * HID * sizeof(bf16), stream);
  lstm_persist<<<dim3(NB), dim3(256), 0, stream>>>(x, Wx, bx, Wh, bh, Wfc, bfc,
                                                   out, flags, hbuf);
}